// Round 2
// baseline (359.687 us; speedup 1.0000x reference)
//
#include <hip/hip_runtime.h>
#include <hip/hip_bf16.h>
#include <type_traits>

// Problem constants: N=4, Sq=2048, Skv=4096, E=1024, H=16, D=64, C=512
// All float tensors are FP32 (per reference); mask is int32; output fp32.
#define NB   4
#define SQ   2048
#define SKV  4096
#define EMB  1024
#define CDIM 512

typedef __attribute__((ext_vector_type(8))) short short8;
typedef __attribute__((ext_vector_type(4))) float f32x4;

__device__ __forceinline__ float b2f(ushort u) {
    union { unsigned int i; float f; } v;
    v.i = ((unsigned int)u) << 16;
    return v.f;
}
__device__ __forceinline__ ushort f2b(float f) {
    union { float f; unsigned int i; } v; v.f = f;
    unsigned int x = v.i;
    return (ushort)((x + 0x7fffu + ((x >> 16) & 1u)) >> 16);   // RNE
}

// ---------------------------------------------------------------------------
// GEMM: C[m,n] = sum_k A[m,k]*B[n,k] + bias[n].
// A: MxK (f32 or bf16-ushort), B: NxK f32, C: MxN (f32 or bf16-ushort).
// f32 operands are converted to bf16 in-register during staging.
// 128x128 tile, BK=32, 4 waves x (4x4) mfma_f32_16x16x32_bf16.
// Fragment layouts (measured m89/m91):
//   A frag: A[m=lane&15][k=(lane>>4)*8+j]; B frag mirrors with Bt rows;
//   C/D: col=lane&15, row=(lane>>4)*4+reg.
// ---------------------------------------------------------------------------
template <typename AT, typename OT>
__global__ __launch_bounds__(256)
void gemm_bt_bias(const AT* __restrict__ A, const float* __restrict__ B,
                  const float* __restrict__ bias, OT* __restrict__ C,
                  int M, int Nn, int K)
{
    __shared__ __attribute__((aligned(16))) ushort As[128 * 32];
    __shared__ __attribute__((aligned(16))) ushort Bs[128 * 32];

    const int tid  = threadIdx.x;
    const int wave = tid >> 6;
    const int lane = tid & 63;
    const int quad = lane >> 4;
    const int l16  = lane & 15;
    const int wr   = wave >> 1;
    const int wc   = wave & 1;

    const long mBase = (long)blockIdx.x * 128;
    const long nBase = (long)blockIdx.y * 128;

    const AT*    Ablk = A + mBase * K;
    const float* Bblk = B + nBase * K;

    f32x4 acc[4][4];
#pragma unroll
    for (int i = 0; i < 4; ++i)
#pragma unroll
        for (int j = 0; j < 4; ++j)
            acc[i][j] = (f32x4){0.f, 0.f, 0.f, 0.f};

    for (int k0 = 0; k0 < K; k0 += 32) {
        // ---- prefetch into registers (before barrier) ----
        float4 aF[4]; int4 aI[2]; float4 bF[4];
        if constexpr (std::is_same<AT, float>::value) {
#pragma unroll
            for (int j = 0; j < 4; ++j) {
                const int flat = j * 1024 + tid * 4;
                const int row = flat >> 5, col = flat & 31;
                aF[j] = *(const float4*)(Ablk + (long)row * K + k0 + col);
            }
        } else {
#pragma unroll
            for (int j = 0; j < 2; ++j) {
                const int flat = j * 2048 + tid * 8;
                const int row = flat >> 5, col = flat & 31;
                aI[j] = *(const int4*)((const ushort*)Ablk + (long)row * K + k0 + col);
            }
        }
#pragma unroll
        for (int j = 0; j < 4; ++j) {
            const int flat = j * 1024 + tid * 4;
            const int row = flat >> 5, col = flat & 31;
            bF[j] = *(const float4*)(Bblk + (long)row * K + k0 + col);
        }

        __syncthreads();   // previous iteration's LDS reads complete

        if constexpr (std::is_same<AT, float>::value) {
#pragma unroll
            for (int j = 0; j < 4; ++j) {
                const int flat = j * 1024 + tid * 4;
                ushort4 c;
                c.x = f2b(aF[j].x); c.y = f2b(aF[j].y);
                c.z = f2b(aF[j].z); c.w = f2b(aF[j].w);
                *(ushort4*)(As + flat) = c;
            }
        } else {
#pragma unroll
            for (int j = 0; j < 2; ++j)
                *(int4*)(As + j * 2048 + tid * 8) = aI[j];
        }
#pragma unroll
        for (int j = 0; j < 4; ++j) {
            const int flat = j * 1024 + tid * 4;
            ushort4 c;
            c.x = f2b(bF[j].x); c.y = f2b(bF[j].y);
            c.z = f2b(bF[j].z); c.w = f2b(bF[j].w);
            *(ushort4*)(Bs + flat) = c;
        }
        __syncthreads();

        short8 af[4], bfr[4];
#pragma unroll
        for (int mt = 0; mt < 4; ++mt)
            af[mt] = *(const short8*)(As + (wr * 64 + mt * 16 + l16) * 32 + quad * 8);
#pragma unroll
        for (int nt = 0; nt < 4; ++nt)
            bfr[nt] = *(const short8*)(Bs + (wc * 64 + nt * 16 + l16) * 32 + quad * 8);

#pragma unroll
        for (int mt = 0; mt < 4; ++mt)
#pragma unroll
            for (int nt = 0; nt < 4; ++nt)
                acc[mt][nt] = __builtin_amdgcn_mfma_f32_16x16x32_bf16(
                    af[mt], bfr[nt], acc[mt][nt], 0, 0, 0);
    }

    // epilogue
#pragma unroll
    for (int mt = 0; mt < 4; ++mt) {
#pragma unroll
        for (int nt = 0; nt < 4; ++nt) {
            const long n = nBase + wc * 64 + nt * 16 + l16;
            const float bv = bias[n];
#pragma unroll
            for (int r = 0; r < 4; ++r) {
                const long m = mBase + wr * 64 + mt * 16 + quad * 4 + r;
                if constexpr (std::is_same<OT, float>::value)
                    C[m * Nn + n] = acc[mt][nt][r] + bv;
                else
                    C[m * Nn + n] = f2b(acc[mt][nt][r] + bv);
            }
        }
    }
}

// ---------------------------------------------------------------------------
// Attention: one block (256 thr) per (n, s2).
//   cq row = (s2 even) ? queries[n,s2/2] (f32) : cond_feat[n,s2/2] (bf16)
//   sc[h,e] = cq[h,:].k[e,:]/8, masked -> softmax -> out = p @ v  (bf16 out)
// LDS rows padded to 68 floats: 16B-aligned float4 + <=2-way bank aliasing.
// ---------------------------------------------------------------------------
__global__ __launch_bounds__(256)
void attn_kernel(const float*  __restrict__ queries,   // (N,Sq,E) f32
                 const ushort* __restrict__ condfeat,  // (N,Sq,E) bf16
                 const float*  __restrict__ keys,      // (N,Skv,E) f32
                 const float*  __restrict__ values,    // (N,Skv,E) f32
                 const int*    __restrict__ mask,      // (N,Skv,16,16) i32
                 ushort* __restrict__ attout)          // (N,Skv,E) bf16
{
    const int pos = blockIdx.x;       // n*SKV + s2
    const int s2  = pos & 4095;
    const int n   = pos >> 12;
    const int tid = threadIdx.x;

    __shared__ __attribute__((aligned(16))) float cq[16 * 68];
    __shared__ __attribute__((aligned(16))) float ks[16 * 68];
    __shared__ __attribute__((aligned(16))) float vs[16 * 68];
    __shared__ float sc[16 * 17];

    {
        const int base = tid * 4;            // 4 elems/thread, 1024 total
        const int h = base >> 6, d = base & 63;
        float4 q4;
        if (s2 & 1) {
            const ushort* cp = condfeat + ((size_t)n * SQ + (s2 >> 1)) * EMB + base;
            ushort4 c4 = *(const ushort4*)cp;
            q4.x = b2f(c4.x); q4.y = b2f(c4.y); q4.z = b2f(c4.z); q4.w = b2f(c4.w);
        } else {
            q4 = *(const float4*)(queries + ((size_t)n * SQ + (s2 >> 1)) * EMB + base);
        }
        float4 k4 = *(const float4*)(keys   + (size_t)pos * EMB + base);
        float4 v4 = *(const float4*)(values + (size_t)pos * EMB + base);
        *(float4*)(cq + h * 68 + d) = q4;
        *(float4*)(ks + h * 68 + d) = k4;
        *(float4*)(vs + h * 68 + d) = v4;
    }
    __syncthreads();

    // scores: one (h,e) per thread; float4 LDS reads
    {
        const int h = tid >> 4, e = tid & 15;
        float s = 0.f;
#pragma unroll
        for (int d = 0; d < 64; d += 4) {
            float4 a = *(const float4*)(cq + h * 68 + d);
            float4 b = *(const float4*)(ks + e * 68 + d);
            s += a.x * b.x + a.y * b.y + a.z * b.z + a.w * b.w;
        }
        s *= 0.125f;                                  // 1/sqrt(64)
        const int mv = mask[(size_t)pos * 256 + tid];
        sc[h * 17 + e] = (mv == 0) ? -1e20f : s;
    }
    __syncthreads();

    // softmax per row; max-subtract so fully-masked rows -> uniform 1/16
    if (tid < 16) {
        const int h = tid;
        float mx = -3e38f;
#pragma unroll
        for (int e = 0; e < 16; ++e) mx = fmaxf(mx, sc[h * 17 + e]);
        float ex[16], sum = 0.f;
#pragma unroll
        for (int e = 0; e < 16; ++e) { ex[e] = __expf(sc[h * 17 + e] - mx); sum += ex[e]; }
        const float inv = 1.f / sum;
#pragma unroll
        for (int e = 0; e < 16; ++e) sc[h * 17 + e] = ex[e] * inv;
    }
    __syncthreads();

    // out[h,d0..d0+3] = sum_e p[h,e]*v[e,d]; 4 outputs/thread via float4
    {
        const int idx = tid * 4;
        const int h = idx >> 6, d0 = idx & 63;
        float4 a = {0.f, 0.f, 0.f, 0.f};
#pragma unroll
        for (int e = 0; e < 16; ++e) {
            const float p = sc[h * 17 + e];
            float4 v4 = *(const float4*)(vs + e * 68 + d0);
            a.x += p * v4.x; a.y += p * v4.y; a.z += p * v4.z; a.w += p * v4.w;
        }
        ushort4 o;
        o.x = f2b(a.x); o.y = f2b(a.y); o.z = f2b(a.z); o.w = f2b(a.w);
        *(ushort4*)(attout + (size_t)pos * EMB + idx) = o;
    }
}

// ---------------------------------------------------------------------------
extern "C" void kernel_launch(void* const* d_in, const int* in_sizes, int n_in,
                              void* d_out, int out_size, void* d_ws, size_t ws_size,
                              hipStream_t stream)
{
    const float* values    = (const float*)d_in[0];
    const float* keys      = (const float*)d_in[1];
    const float* queries   = (const float*)d_in[2];
    const int*   mask      = (const int*)  d_in[3];
    const float* condition = (const float*)d_in[4];
    const float* Wc        = (const float*)d_in[5];
    const float* bc        = (const float*)d_in[6];
    const float* Wo        = (const float*)d_in[7];
    const float* bo        = (const float*)d_in[8];
    float* out = (float*)d_out;

    // workspace: cond_feat bf16 (8192x1024, 16MB) + att_out bf16 (16384x1024, 32MB)
    ushort* condfeat = (ushort*)d_ws;
    ushort* attout   = condfeat + (size_t)NB * SQ * EMB;

    // 1) cond_feat = condition(8192x512 f32) @ Wc^T(1024x512 f32) + bc -> bf16
    {
        dim3 grid((NB * SQ) / 128, EMB / 128);   // 64 x 8
        gemm_bt_bias<float, ushort><<<grid, 256, 0, stream>>>(
            condition, Wc, bc, condfeat, NB * SQ, EMB, CDIM);
    }

    // 2) per-position 16x16 attention -> att_out (bf16)
    attn_kernel<<<NB * SKV, 256, 0, stream>>>(queries, condfeat, keys, values,
                                              mask, attout);

    // 3) out = att_out(16384x1024 bf16) @ Wo^T(1024x1024 f32) + bo -> f32
    {
        dim3 grid((NB * SKV) / 128, EMB / 128);  // 128 x 8
        gemm_bt_bias<ushort, float><<<grid, 256, 0, stream>>>(
            attout, Wo, bo, out, NB * SKV, EMB, EMB);
    }
}

// Round 3
// 302.668 us; speedup vs baseline: 1.1884x; 1.1884x over previous
//
#include <hip/hip_runtime.h>
#include <hip/hip_bf16.h>
#include <type_traits>

// Problem constants: N=4, Sq=2048, Skv=4096, E=1024, H=16, D=64, C=512
// Float tensors are FP32 in global; mask int32; output fp32.
#define NB   4
#define SQ   2048
#define SKV  4096
#define EMB  1024
#define CDIM 512

typedef __attribute__((ext_vector_type(8))) short short8;
typedef __attribute__((ext_vector_type(4))) float f32x4;

__device__ __forceinline__ float b2f(ushort u) {
    union { unsigned int i; float f; } v;
    v.i = ((unsigned int)u) << 16;
    return v.f;
}
__device__ __forceinline__ ushort f2b(float f) {
    union { float f; unsigned int i; } v; v.f = f;
    unsigned int x = v.i;
    return (ushort)((x + 0x7fffu + ((x >> 16) & 1u)) >> 16);   // RNE
}

// async global->LDS, 16B per lane; LDS dest = wave-uniform base + lane*16
__device__ __forceinline__ void glds16(const ushort* gp, ushort* lp) {
    __builtin_amdgcn_global_load_lds(
        (const __attribute__((address_space(1))) unsigned int*)gp,
        (__attribute__((address_space(3))) unsigned int*)lp,
        16, 0, 0);
}

// ---------------------------------------------------------------------------
// f32 -> bf16 bulk convert (memory-bound, float4/ushort4)
// ---------------------------------------------------------------------------
__global__ __launch_bounds__(256)
void cvt_f32_bf16(const float* __restrict__ in, ushort* __restrict__ out, int n4)
{
    const int i = blockIdx.x * 256 + threadIdx.x;
    if (i < n4) {
        float4 v = ((const float4*)in)[i];
        ushort4 o;
        o.x = f2b(v.x); o.y = f2b(v.y); o.z = f2b(v.z); o.w = f2b(v.w);
        ((ushort4*)out)[i] = o;
    }
}

// ---------------------------------------------------------------------------
// Pure-bf16 GEMM (m97 structure): C[m,n] = sum_k A[m,k]*B[n,k] + bias[n]
// A: MxK bf16, B: NxK bf16 (both row-major, K-contiguous), bias f32,
// C: MxN (f32 or bf16).  128x128 tile, BK=32, 4 waves x (4x4)
// mfma_f32_16x16x32_bf16, staging via global_load_lds width=16.
// LDS layout is linear 128x32 (required by glds lane mapping); the 8-way
// fragment-read aliasing (~4M SQ_LDS_BANK_CONFLICT) is the known m97/m98
// pattern and overlaps with MFMA.
// ---------------------------------------------------------------------------
template <typename OT>
__global__ __launch_bounds__(256)
void gemm_bt_bias(const ushort* __restrict__ A, const ushort* __restrict__ B,
                  const float* __restrict__ bias, OT* __restrict__ C,
                  int M, int Nn, int K)
{
    __shared__ __attribute__((aligned(16))) ushort As[128 * 32];
    __shared__ __attribute__((aligned(16))) ushort Bs[128 * 32];

    const int tid  = threadIdx.x;
    const int wave = tid >> 6;
    const int lane = tid & 63;
    const int quad = lane >> 4;
    const int l16  = lane & 15;
    const int wr   = wave >> 1;   // wave row (64 rows of M)
    const int wc   = wave & 1;    // wave col (64 cols of N)

    const long mBase = (long)blockIdx.x * 128;
    const long nBase = (long)blockIdx.y * 128;

    const ushort* Ablk = A + mBase * K;
    const ushort* Bblk = B + nBase * K;

    // staging map: chunk c (1 KB) covers rows [c*16, c*16+16), lane l ->
    // row c*16 + l/4, col (l&3)*8.  Wave w owns chunks 2w, 2w+1 of A and B.
    const int lr = lane >> 2;
    const int lc = (lane & 3) * 8;
    const int c0 = wave * 2, c1 = wave * 2 + 1;
    const ushort* aG0 = Ablk + (long)(c0 * 16 + lr) * K + lc;
    const ushort* aG1 = Ablk + (long)(c1 * 16 + lr) * K + lc;
    const ushort* bG0 = Bblk + (long)(c0 * 16 + lr) * K + lc;
    const ushort* bG1 = Bblk + (long)(c1 * 16 + lr) * K + lc;
    ushort* aL0 = As + c0 * 512;
    ushort* aL1 = As + c1 * 512;
    ushort* bL0 = Bs + c0 * 512;
    ushort* bL1 = Bs + c1 * 512;

    f32x4 acc[4][4];
#pragma unroll
    for (int i = 0; i < 4; ++i)
#pragma unroll
        for (int j = 0; j < 4; ++j)
            acc[i][j] = (f32x4){0.f, 0.f, 0.f, 0.f};

    for (int k0 = 0; k0 < K; k0 += 32) {
        __syncthreads();              // previous iteration's LDS reads done
        glds16(aG0 + k0, aL0);
        glds16(aG1 + k0, aL1);
        glds16(bG0 + k0, bL0);
        glds16(bG1 + k0, bL1);
        __syncthreads();              // vmcnt(0) drained before barrier

        short8 af[4], bfr[4];
#pragma unroll
        for (int mt = 0; mt < 4; ++mt)
            af[mt] = *(const short8*)(As + (wr * 64 + mt * 16 + l16) * 32 + quad * 8);
#pragma unroll
        for (int nt = 0; nt < 4; ++nt)
            bfr[nt] = *(const short8*)(Bs + (wc * 64 + nt * 16 + l16) * 32 + quad * 8);

#pragma unroll
        for (int mt = 0; mt < 4; ++mt)
#pragma unroll
            for (int nt = 0; nt < 4; ++nt)
                acc[mt][nt] = __builtin_amdgcn_mfma_f32_16x16x32_bf16(
                    af[mt], bfr[nt], acc[mt][nt], 0, 0, 0);
    }

    // epilogue: C[m,n] = acc + bias[n]
#pragma unroll
    for (int mt = 0; mt < 4; ++mt) {
#pragma unroll
        for (int nt = 0; nt < 4; ++nt) {
            const long n = nBase + wc * 64 + nt * 16 + l16;
            const float bv = bias[n];
#pragma unroll
            for (int r = 0; r < 4; ++r) {
                const long m = mBase + wr * 64 + mt * 16 + quad * 4 + r;
                if constexpr (std::is_same<OT, float>::value)
                    C[m * Nn + n] = acc[mt][nt][r] + bv;
                else
                    C[m * Nn + n] = f2b(acc[mt][nt][r] + bv);
            }
        }
    }
}

// ---------------------------------------------------------------------------
// Attention: one block (256 thr) per (n, s2).
//   cq row = (s2 even) ? queries[n,s2/2] (f32) : cond_feat[n,s2/2] (bf16)
//   sc[h,e] = cq[h,:].k[e,:]/8, masked -> softmax(e) -> out = p @ v (bf16)
// Softmax: 16-lane shuffle butterflies on all 256 threads (no serial phase).
// LDS rows padded to 68 floats (16B-aligned float4, <=2-way bank aliasing).
// ---------------------------------------------------------------------------
__global__ __launch_bounds__(256)
void attn_kernel(const float*  __restrict__ queries,   // (N,Sq,E) f32
                 const ushort* __restrict__ condfeat,  // (N,Sq,E) bf16
                 const float*  __restrict__ keys,      // (N,Skv,E) f32
                 const float*  __restrict__ values,    // (N,Skv,E) f32
                 const int*    __restrict__ mask,      // (N,Skv,16,16) i32
                 ushort* __restrict__ attout)          // (N,Skv,E) bf16
{
    const int pos = blockIdx.x;       // n*SKV + s2
    const int s2  = pos & 4095;
    const int n   = pos >> 12;
    const int tid = threadIdx.x;

    __shared__ __attribute__((aligned(16))) float cq[16 * 68];
    __shared__ __attribute__((aligned(16))) float ks[16 * 68];
    __shared__ __attribute__((aligned(16))) float vs[16 * 68];
    __shared__ float sc[16 * 17];

    {
        const int base = tid * 4;            // 4 elems/thread, 1024 total
        const int h = base >> 6, d = base & 63;
        float4 q4;
        if (s2 & 1) {
            const ushort* cp = condfeat + ((size_t)n * SQ + (s2 >> 1)) * EMB + base;
            ushort4 c4 = *(const ushort4*)cp;
            q4.x = b2f(c4.x); q4.y = b2f(c4.y); q4.z = b2f(c4.z); q4.w = b2f(c4.w);
        } else {
            q4 = *(const float4*)(queries + ((size_t)n * SQ + (s2 >> 1)) * EMB + base);
        }
        float4 k4 = *(const float4*)(keys   + (size_t)pos * EMB + base);
        float4 v4 = *(const float4*)(values + (size_t)pos * EMB + base);
        *(float4*)(cq + h * 68 + d) = q4;
        *(float4*)(ks + h * 68 + d) = k4;
        *(float4*)(vs + h * 68 + d) = v4;
    }
    __syncthreads();

    // scores + shuffle softmax: thread (h = tid>>4, e = tid&15)
    {
        const int h = tid >> 4, e = tid & 15;
        float s = 0.f;
#pragma unroll
        for (int d = 0; d < 64; d += 4) {
            float4 a = *(const float4*)(cq + h * 68 + d);
            float4 b = *(const float4*)(ks + e * 68 + d);
            s += a.x * b.x + a.y * b.y + a.z * b.z + a.w * b.w;
        }
        s *= 0.125f;                                  // 1/sqrt(64)
        const int mv = mask[(size_t)pos * 256 + tid];
        s = (mv == 0) ? -1e20f : s;

        float mx = s;
#pragma unroll
        for (int d = 1; d < 16; d <<= 1)
            mx = fmaxf(mx, __shfl_xor(mx, d));
        const float ex = __expf(s - mx);              // fully-masked row -> 1/16
        float sum = ex;
#pragma unroll
        for (int d = 1; d < 16; d <<= 1)
            sum += __shfl_xor(sum, d);
        sc[h * 17 + e] = ex / sum;
    }
    __syncthreads();

    // out[h,d0..d0+3] = sum_e p[h,e]*v[e,d]
    {
        const int idx = tid * 4;
        const int h = idx >> 6, d0 = idx & 63;
        float4 a = {0.f, 0.f, 0.f, 0.f};
#pragma unroll
        for (int e = 0; e < 16; ++e) {
            const float p = sc[h * 17 + e];
            float4 v4 = *(const float4*)(vs + e * 68 + d0);
            a.x += p * v4.x; a.y += p * v4.y; a.z += p * v4.z; a.w += p * v4.w;
        }
        ushort4 o;
        o.x = f2b(a.x); o.y = f2b(a.y); o.z = f2b(a.z); o.w = f2b(a.w);
        *(ushort4*)(attout + (size_t)pos * EMB + idx) = o;
    }
}

// ---------------------------------------------------------------------------
extern "C" void kernel_launch(void* const* d_in, const int* in_sizes, int n_in,
                              void* d_out, int out_size, void* d_ws, size_t ws_size,
                              hipStream_t stream)
{
    const float* values    = (const float*)d_in[0];
    const float* keys      = (const float*)d_in[1];
    const float* queries   = (const float*)d_in[2];
    const int*   mask      = (const int*)  d_in[3];
    const float* condition = (const float*)d_in[4];
    const float* Wc        = (const float*)d_in[5];
    const float* bc        = (const float*)d_in[6];
    const float* Wo        = (const float*)d_in[7];
    const float* bo        = (const float*)d_in[8];
    float* out = (float*)d_out;

    // workspace (48 MB total, with liveness-based aliasing):
    //  [0,16MB)  condfeat bf16 (8192x1024)      live: gemm1 -> attn
    //  [16,48MB) attout  bf16 (16384x1024)      live: attn -> gemm3
    //  cond_bf (8MB) + Wc_bf (1MB) alias attout (dead before attn writes it)
    //  Wo_bf (2MB) aliases condfeat (converted after attn, condfeat then dead)
    ushort* condfeat = (ushort*)d_ws;
    ushort* attout   = condfeat + (size_t)NB * SQ * EMB;
    ushort* cond_bf  = attout;
    ushort* Wc_bf    = attout + (size_t)NB * SQ * CDIM;
    ushort* Wo_bf    = condfeat;

    // converts needed before gemm1
    cvt_f32_bf16<<<(NB * SQ * CDIM / 4 + 255) / 256, 256, 0, stream>>>(
        condition, cond_bf, NB * SQ * CDIM / 4);
    cvt_f32_bf16<<<(EMB * CDIM / 4 + 255) / 256, 256, 0, stream>>>(
        Wc, Wc_bf, EMB * CDIM / 4);

    // 1) cond_feat = condition @ Wc^T + bc   (8192x1024, K=512) -> bf16
    {
        dim3 grid((NB * SQ) / 128, EMB / 128);
        gemm_bt_bias<ushort><<<grid, 256, 0, stream>>>(
            cond_bf, Wc_bf, bc, condfeat, NB * SQ, EMB, CDIM);
    }

    // 2) per-position 16x16 attention -> att_out (bf16)
    attn_kernel<<<NB * SKV, 256, 0, stream>>>(queries, condfeat, keys, values,
                                              mask, attout);

    // convert Wo after attn (aliases dead condfeat)
    cvt_f32_bf16<<<(EMB * EMB / 4 + 255) / 256, 256, 0, stream>>>(
        Wo, Wo_bf, EMB * EMB / 4);

    // 3) out = att_out @ Wo^T + bo   (16384x1024, K=1024) -> f32
    {
        dim3 grid((NB * SKV) / 128, EMB / 128);
        gemm_bt_bias<float><<<grid, 256, 0, stream>>>(
            attout, Wo_bf, bo, out, NB * SKV, EMB, EMB);
    }
}